// Round 1
// baseline (2308.768 us; speedup 1.0000x reference)
//
#include <hip/hip_runtime.h>

#define B_   128
#define T_   500
#define C_   700
#define CP_  704        // C padded to multiple of 16 (zero-filled)
#define H_   1024
#define O_   20
#define M_   (T_ * B_)  // 64000 rows, row = t*128 + b

// workspace layout (in floats)
#define OFF_WINT   0u                               // [CP_][H_]   w_in^T (zero-padded rows)
#define OFF_WRECT  (OFF_WINT  + (size_t)CP_ * H_)   // [H_][H_]    w_rec^T
#define OFF_WOUTT  (OFF_WRECT + (size_t)H_ * H_)    // [H_][O_]    w_out^T
#define OFF_XD     (OFF_WOUTT + (size_t)H_ * O_)    // [M_][CP_]   delayed input
#define OFF_IIN    (OFF_XD    + (size_t)M_ * CP_)   // [M_][H_]    feed-forward currents
// total ~= 112.4M floats ~= 450 MB

// ---------------------------------------------------------------------------
// Generic transpose with zero-padded extra output rows:
//   out[c*R + r] = (c < C) ? in[r*C + c] : 0   for c in [0, Cpad)
__global__ __launch_bounds__(256) void transpose_pad(
    const float* __restrict__ in, float* __restrict__ out,
    int R, int C, int Cpad) {
  int idx = blockIdx.x * 256 + threadIdx.x;
  int total = Cpad * R;
  if (idx >= total) return;
  int c = idx / R;
  int r = idx - c * R;
  out[idx] = (c < C) ? in[(size_t)r * C + c] : 0.0f;
}

// ---------------------------------------------------------------------------
// xd[(t*B + b)*CP_ + c] = (t >= d_c) ? x[b, t - d_c, c] : 0
__global__ __launch_bounds__(256) void delay_shift(
    const float* __restrict__ x, const int* __restrict__ delays,
    float* __restrict__ xd) {
  int row = blockIdx.x;          // t*128 + b
  int t = row >> 7;
  int b = row & 127;
  const float* xb = x + (size_t)b * (T_ * C_);
  float* dst = xd + (size_t)row * CP_;
  for (int c = threadIdx.x; c < CP_; c += 256) {
    float v = 0.0f;
    if (c < C_) {
      int ts = t - delays[c];
      if (ts >= 0) v = xb[(size_t)ts * C_ + c];
    }
    dst[c] = v;
  }
}

// ---------------------------------------------------------------------------
// fp32 tiled GEMM: C[M_,H_] = A[M_,CP_] * B[CP_,H_]
// 128x128 tile, BK=16, 256 threads, 8x8 per-thread microtile.
__global__ __launch_bounds__(256) void gemm_f32(
    const float* __restrict__ A, const float* __restrict__ Bm,
    float* __restrict__ Cm) {
  __shared__ float As[16][132];
  __shared__ float Bs[16][132];
  const int row0 = blockIdx.x * 128;
  const int col0 = blockIdx.y * 128;
  const int tid = threadIdx.x;
  const int tx = tid & 15, ty = tid >> 4;

  float acc[8][8];
#pragma unroll
  for (int i = 0; i < 8; ++i)
#pragma unroll
    for (int j = 0; j < 8; ++j) acc[i][j] = 0.0f;

  const int ai = tid >> 1;            // A row within tile
  const int ak = (tid & 1) * 8;       // A k-offset
  const int bk = tid >> 4;            // B k-row within tile
  const int bn = (tid & 15) * 8;      // B col-offset
  const float* aptr = A + (size_t)(row0 + ai) * CP_ + ak;
  const float* bptr = Bm + (size_t)bk * H_ + col0 + bn;

  for (int k0 = 0; k0 < CP_; k0 += 16) {
    float4 a0 = *(const float4*)(aptr);
    float4 a1 = *(const float4*)(aptr + 4);
    float4 b0 = *(const float4*)(bptr);
    float4 b1 = *(const float4*)(bptr + 4);
    As[ak + 0][ai] = a0.x; As[ak + 1][ai] = a0.y;
    As[ak + 2][ai] = a0.z; As[ak + 3][ai] = a0.w;
    As[ak + 4][ai] = a1.x; As[ak + 5][ai] = a1.y;
    As[ak + 6][ai] = a1.z; As[ak + 7][ai] = a1.w;
    *(float4*)&Bs[bk][bn]     = b0;
    *(float4*)&Bs[bk][bn + 4] = b1;
    __syncthreads();
#pragma unroll
    for (int kk = 0; kk < 16; ++kk) {
      float4 x0 = *(const float4*)&As[kk][ty * 8];
      float4 x1 = *(const float4*)&As[kk][ty * 8 + 4];
      float4 y0 = *(const float4*)&Bs[kk][tx * 8];
      float4 y1 = *(const float4*)&Bs[kk][tx * 8 + 4];
      float av[8] = {x0.x, x0.y, x0.z, x0.w, x1.x, x1.y, x1.z, x1.w};
      float bv[8] = {y0.x, y0.y, y0.z, y0.w, y1.x, y1.y, y1.z, y1.w};
#pragma unroll
      for (int i = 0; i < 8; ++i)
#pragma unroll
        for (int j = 0; j < 8; ++j)
          acc[i][j] = fmaf(av[i], bv[j], acc[i][j]);
    }
    __syncthreads();
    aptr += 16;
    bptr += (size_t)16 * H_;
  }
#pragma unroll
  for (int i = 0; i < 8; ++i) {
    float* crow = Cm + (size_t)(row0 + ty * 8 + i) * H_ + col0 + tx * 8;
    float4 c0 = {acc[i][0], acc[i][1], acc[i][2], acc[i][3]};
    float4 c1 = {acc[i][4], acc[i][5], acc[i][6], acc[i][7]};
    *(float4*)crow = c0;
    *(float4*)(crow + 4) = c1;
  }
}

// ---------------------------------------------------------------------------
// One block per batch sample b; 256 threads x 4 neurons each.
// State (v, a, spk) in registers; spike list double-buffered in LDS.
__global__ __launch_bounds__(256) void recurrent(
    const float* __restrict__ Iin,   // [M_][H_], row = t*128 + b
    const float* __restrict__ wrecT, // [H_][H_]   wrecT[h'][h] = w_rec[h][h']
    const float* __restrict__ woutT, // [H_][O_]   woutT[h][o]  = w_out[o][h]
    const float* __restrict__ alpha, const float* __restrict__ rho,
    const float* __restrict__ beta_a, const float* __restrict__ beta_out,
    float* __restrict__ out) {
  __shared__ int cnt[2];
  __shared__ int lst[2][H_];
  __shared__ float IoutS[O_];

  const int b = blockIdx.x;
  const int tid = threadIdx.x;
  const int h0 = tid * 4;

  float4 v  = {0.f, 0.f, 0.f, 0.f};
  float4 aa = {0.f, 0.f, 0.f, 0.f};
  float4 sp = {0.f, 0.f, 0.f, 0.f};
  const float4 al = *(const float4*)(alpha + h0);
  const float4 rh = *(const float4*)(rho + h0);
  const float4 ba = *(const float4*)(beta_a + h0);

  float vo = 0.f, osum = 0.f, bo = 0.f;
  if (tid < O_) { bo = beta_out[tid]; IoutS[tid] = 0.f; }
  if (tid < 2) cnt[tid] = 0;

  const float* base = Iin + (size_t)b * H_ + h0;
  float4 nxt = *(const float4*)(base);   // t = 0
  int p = 0;
  __syncthreads();

  for (int t = 0; t < T_; ++t) {
    float4 cur = nxt;
    if (t + 1 < T_)  // prefetch next timestep's current (state-independent)
      nxt = *(const float4*)(base + (size_t)(t + 1) * (B_ * H_));

    // I = Iin[t] + sum over previous-step spikes of w_rec columns
    float4 I = cur;
    const int ns = cnt[p];
    for (int s = 0; s < ns; ++s) {
      const int hp = lst[p][s];
      const float4 w = *(const float4*)(wrecT + (size_t)hp * H_ + h0);
      I.x += w.x; I.y += w.y; I.z += w.z; I.w += w.w;
    }

    // adaptive LIF pointwise update (matches reference formula exactly)
    float4 vn, sn;
    vn.x = al.x * v.x * (1.0f - sp.x) + (1.0f - al.x) * (I.x - aa.x);
    vn.y = al.y * v.y * (1.0f - sp.y) + (1.0f - al.y) * (I.y - aa.y);
    vn.z = al.z * v.z * (1.0f - sp.z) + (1.0f - al.z) * (I.z - aa.z);
    vn.w = al.w * v.w * (1.0f - sp.w) + (1.0f - al.w) * (I.w - aa.w);
    sn.x = (vn.x > 1.0f) ? 1.0f : 0.0f;
    sn.y = (vn.y > 1.0f) ? 1.0f : 0.0f;
    sn.z = (vn.z > 1.0f) ? 1.0f : 0.0f;
    sn.w = (vn.w > 1.0f) ? 1.0f : 0.0f;
    aa.x = rh.x * aa.x + (1.0f - rh.x) * (ba.x * vn.x + sn.x);
    aa.y = rh.y * aa.y + (1.0f - rh.y) * (ba.y * vn.y + sn.y);
    aa.z = rh.z * aa.z + (1.0f - rh.z) * (ba.z * vn.z + sn.z);
    aa.w = rh.w * aa.w + (1.0f - rh.w) * (ba.w * vn.w + sn.w);
    v = vn; sp = sn;

    __syncthreads();  // A: all done reading lst[p]/cnt[p]; zeroed bufs visible

    // append new spikes to other buffer; accumulate output currents
#pragma unroll
    for (int j = 0; j < 4; ++j) {
      const float s = (j == 0) ? sn.x : (j == 1) ? sn.y : (j == 2) ? sn.z : sn.w;
      if (s > 0.0f) {
        const int h = h0 + j;
        const int idx = atomicAdd(&cnt[1 - p], 1);
        lst[1 - p][idx] = h;
        const float* wo = woutT + (size_t)h * O_;
#pragma unroll
        for (int o = 0; o < O_; ++o) atomicAdd(&IoutS[o], wo[o]);
      }
    }

    __syncthreads();  // B: new list + IoutS complete

    if (tid < O_) {
      const float io = IoutS[tid];
      vo = bo * vo + (1.0f - bo) * io;
      osum += vo;
      IoutS[tid] = 0.f;      // re-zero for next step (same-thread order)
    }
    if (tid == 0) cnt[p] = 0;  // retire old buffer
    p ^= 1;
  }

  if (tid < O_) out[b * O_ + tid] = osum / (float)T_;
}

// ---------------------------------------------------------------------------
extern "C" void kernel_launch(void* const* d_in, const int* in_sizes, int n_in,
                              void* d_out, int out_size, void* d_ws, size_t ws_size,
                              hipStream_t stream) {
  const float* x        = (const float*)d_in[0];
  const int*   delays   = (const int*)d_in[1];
  const float* w_in     = (const float*)d_in[2];
  const float* w_rec    = (const float*)d_in[3];
  const float* w_out    = (const float*)d_in[4];
  const float* alpha    = (const float*)d_in[5];
  const float* rho      = (const float*)d_in[6];
  const float* beta_a   = (const float*)d_in[7];
  const float* beta_out = (const float*)d_in[8];

  float* ws      = (float*)d_ws;
  float* w_in_T  = ws + OFF_WINT;
  float* w_rec_T = ws + OFF_WRECT;
  float* w_out_T = ws + OFF_WOUTT;
  float* xd      = ws + OFF_XD;
  float* Iin     = ws + OFF_IIN;
  float* out     = (float*)d_out;

  transpose_pad<<<(CP_ * H_) / 256, 256, 0, stream>>>(w_in, w_in_T, H_, C_, CP_);
  transpose_pad<<<(H_ * H_) / 256, 256, 0, stream>>>(w_rec, w_rec_T, H_, H_, H_);
  transpose_pad<<<(H_ * O_) / 256, 256, 0, stream>>>(w_out, w_out_T, O_, H_, H_);

  delay_shift<<<M_, 256, 0, stream>>>(x, delays, xd);

  dim3 g(M_ / 128, H_ / 128);
  gemm_f32<<<g, 256, 0, stream>>>(xd, w_in_T, Iin);

  recurrent<<<B_, 256, 0, stream>>>(Iin, w_rec_T, w_out_T,
                                    alpha, rho, beta_a, beta_out, out);
}

// Round 2
// 1369.239 us; speedup vs baseline: 1.6862x; 1.6862x over previous
//
#include <hip/hip_runtime.h>
#include <stdint.h>

#define B_   128
#define T_   500
#define C_   700
#define CP_  704          // C padded to 16
#define H_   1024
#define O_   20
#define M_   (T_ * B_)    // 64000 rows, row = t*128 + b
#define KA_  (2 * CP_)    // 1408: A' = [hi | lo]
#define KB_  (3 * CP_)    // 2112: Bt = [hi | hi | lo]
#define SCALE_      256.0f
#define INV_SCALE2_ (1.0f / 65536.0f)

typedef _Float16 half8 __attribute__((ext_vector_type(8)));
typedef float    f32x4 __attribute__((ext_vector_type(4)));

// ---------------------------------------------------------------------------
// out[c*R + r] = (c < C) ? in[r*C + c] : 0   (fp32 transpose, zero-pad)
__global__ __launch_bounds__(256) void transpose_pad(
    const float* __restrict__ in, float* __restrict__ out,
    int R, int C, int Cpad) {
  int idx = blockIdx.x * 256 + threadIdx.x;
  if (idx >= Cpad * R) return;
  int c = idx / R;
  int r = idx - c * R;
  out[idx] = (c < C) ? in[(size_t)r * C + c] : 0.0f;
}

// ---------------------------------------------------------------------------
// Bt[n][k]: k in [0,704) -> hi(w*256); [704,1408) -> hi; [1408,2112) -> lo
__global__ __launch_bounds__(256) void bt_prep(
    const float* __restrict__ w_in, _Float16* __restrict__ Bt) {
  int idx = blockIdx.x * 256 + threadIdx.x;   // over H_*KB_
  if (idx >= H_ * KB_) return;
  int n = idx / KB_;
  int k = idx - n * KB_;
  int blk = k / CP_;
  int c = k - blk * CP_;
  float v = (c < C_) ? w_in[(size_t)n * C_ + c] * SCALE_ : 0.0f;
  _Float16 hi = (_Float16)v;
  Bt[idx] = (blk == 2) ? (_Float16)(v - (float)hi) : hi;
}

// ---------------------------------------------------------------------------
// A3[m][k]: k in [0,704) -> hi(xd*256); [704,1408) -> lo.  m = t*128+b.
__global__ __launch_bounds__(256) void delay_split(
    const float* __restrict__ x, const int* __restrict__ delays,
    _Float16* __restrict__ A3) {
  int row = blockIdx.x;
  int t = row >> 7;
  int b = row & 127;
  const float* xb = x + (size_t)b * (T_ * C_);
  _Float16* dst = A3 + (size_t)row * KA_;
  for (int c = threadIdx.x; c < CP_; c += 256) {
    float v = 0.0f;
    if (c < C_) {
      int ts = t - delays[c];
      if (ts >= 0) v = xb[(size_t)ts * C_ + c];
    }
    v *= SCALE_;
    _Float16 hi = (_Float16)v;
    dst[c] = hi;
    dst[CP_ + c] = (_Float16)(v - (float)hi);
  }
}

// ---------------------------------------------------------------------------
__device__ __forceinline__ void gload16(const void* g, const void* l) {
  __builtin_amdgcn_global_load_lds(
      (const __attribute__((address_space(1))) void*)(uintptr_t)g,
      (__attribute__((address_space(3))) void*)(uint32_t)(uintptr_t)l,
      16, 0, 0);
}

// fp16 MFMA GEMM: Cm[M_,H_] = A3[M_,KA_ (hi reused)] x Bt[H_,KB_]^T, *2^-16.
// 128x128 tile, BK=32, 256 threads = 4 waves (2x2 of 64x64), single-buffered
// LDS with global_load_lds width-16 staging, XOR chunk swizzle (2-way = free).
__global__ __launch_bounds__(256) void gemm_split(
    const _Float16* __restrict__ A3, const _Float16* __restrict__ Bt,
    float* __restrict__ Cm) {
  __shared__ __align__(16) _Float16 As[128 * 32];
  __shared__ __align__(16) _Float16 Bs[128 * 32];

  const int tid  = threadIdx.x;
  const int wave = tid >> 6, lane = tid & 63;
  const int col0 = blockIdx.x * 128;   // N tile (x fastest: Bt stays in L2,
  const int row0 = blockIdx.y * 128;   //  A3 row-block read once per sweep)
  const int q = lane >> 4, r = lane & 15;
  const int wm0 = (wave >> 1) * 64, wn0 = (wave & 1) * 64;

  f32x4 acc[4][4] = {};

  // staging: wave covers rows [wave*32, wave*32+32) via 2 passes of 16 rows
  const int pi0 = wave * 2;
  const int srow = lane >> 2;                              // row within pass
  const int gch8 = (((lane & 3) ^ ((lane >> 3) & 3))) * 8; // swizzled chunk (halves)

  // fragment LDS offsets (halves), fixed across iterations
  const int ch8 = (q ^ ((r >> 1) & 3)) * 8;
  int aoff[4], boff[4];
#pragma unroll
  for (int i = 0; i < 4; ++i) {
    aoff[i] = (wm0 + i * 16 + r) * 32 + ch8;
    boff[i] = (wn0 + i * 16 + r) * 32 + ch8;
  }

  const size_t arow0 = (size_t)(row0 + pi0 * 16 + srow);
  const size_t arow1 = arow0 + 16;
  const size_t brow0 = (size_t)(col0 + pi0 * 16 + srow);
  const size_t brow1 = brow0 + 16;

  for (int kb = 0; kb < KB_ / 32; ++kb) {
    const int k0 = kb * 32;
    const int kA = (k0 < KA_) ? k0 : (k0 - KA_);   // hi block reused for pass 3
    __syncthreads();
    gload16(A3 + arow0 * KA_ + kA + gch8, &As[(pi0 + 0) * 512]);
    gload16(A3 + arow1 * KA_ + kA + gch8, &As[(pi0 + 1) * 512]);
    gload16(Bt + brow0 * KB_ + k0 + gch8, &Bs[(pi0 + 0) * 512]);
    gload16(Bt + brow1 * KB_ + k0 + gch8, &Bs[(pi0 + 1) * 512]);
    __syncthreads();

    half8 af[4], bf[4];
#pragma unroll
    for (int i = 0; i < 4; ++i) af[i] = *(const half8*)&As[aoff[i]];
#pragma unroll
    for (int j = 0; j < 4; ++j) bf[j] = *(const half8*)&Bs[boff[j]];
#pragma unroll
    for (int i = 0; i < 4; ++i)
#pragma unroll
      for (int j = 0; j < 4; ++j)
        acc[i][j] = __builtin_amdgcn_mfma_f32_16x16x32_f16(af[i], bf[j],
                                                           acc[i][j], 0, 0, 0);
  }

  // C/D layout (m89-verified): col = lane&15, row = quad*4 + reg
#pragma unroll
  for (int i = 0; i < 4; ++i) {
    const int mrow = row0 + wm0 + i * 16 + q * 4;
#pragma unroll
    for (int j = 0; j < 4; ++j) {
      const int ncol = col0 + wn0 + j * 16 + r;
      float* cp = Cm + (size_t)mrow * H_ + ncol;
#pragma unroll
      for (int rg = 0; rg < 4; ++rg)
        cp[(size_t)rg * H_] = acc[i][j][rg] * INV_SCALE2_;
    }
  }
}

// ---------------------------------------------------------------------------
// One wave (64 lanes) per batch sample; 16 neurons per lane (h = lane*16+j).
// Spike exchange via in-register ballots -> no LDS, no barriers.
__global__ __launch_bounds__(64) void recurrent_w(
    const float* __restrict__ Iin,   // [M_][H_], row = t*128 + b
    const float* __restrict__ wrecT, // [H_][H_]  wrecT[h'][h] = w_rec[h][h']
    const float* __restrict__ woutT, // [H_][O_]  woutT[h][o]  = w_out[o][h]
    const float* __restrict__ alpha, const float* __restrict__ rho,
    const float* __restrict__ beta_a, const float* __restrict__ beta_out,
    float* __restrict__ out) {
  const int b = blockIdx.x;
  const int lane = threadIdx.x;
  const int h0 = lane * 16;

  float v[16], av[16], spk[16];
  float al[16], al1[16], rh[16], rh1[16], ba[16];
#pragma unroll
  for (int j = 0; j < 16; ++j) {
    v[j] = 0.f; av[j] = 0.f; spk[j] = 0.f;
    al[j] = alpha[h0 + j]; al1[j] = 1.0f - al[j];
    rh[j] = rho[h0 + j];   rh1[j] = 1.0f - rh[j];
    ba[j] = beta_a[h0 + j];
  }
  unsigned long long bmask[16];
#pragma unroll
  for (int j = 0; j < 16; ++j) bmask[j] = 0ull;

  const int olane = (lane < O_) ? lane : 0;
  float bo = 0.f, vo = 0.f, osum = 0.f;
  if (lane < O_) bo = beta_out[lane];

  const float* base = Iin + (size_t)b * H_ + h0;
  float4 nx0 = *(const float4*)(base + 0);
  float4 nx1 = *(const float4*)(base + 4);
  float4 nx2 = *(const float4*)(base + 8);
  float4 nx3 = *(const float4*)(base + 12);

  for (int t = 0; t < T_; ++t) {
    float I[16];
    I[0]  = nx0.x; I[1]  = nx0.y; I[2]  = nx0.z; I[3]  = nx0.w;
    I[4]  = nx1.x; I[5]  = nx1.y; I[6]  = nx1.z; I[7]  = nx1.w;
    I[8]  = nx2.x; I[9]  = nx2.y; I[10] = nx2.z; I[11] = nx2.w;
    I[12] = nx3.x; I[13] = nx3.y; I[14] = nx3.z; I[15] = nx3.w;
    if (t + 1 < T_) {
      const float* nb = base + (size_t)(t + 1) * (B_ * H_);
      nx0 = *(const float4*)(nb + 0);
      nx1 = *(const float4*)(nb + 4);
      nx2 = *(const float4*)(nb + 8);
      nx3 = *(const float4*)(nb + 12);
    }

    // recurrent input from previous-step spikes (masks are wave-uniform ->
    // scalar loop; vector loads of 64B/lane, fully coalesced, L2-resident)
#pragma unroll
    for (int j = 0; j < 16; ++j) {
      unsigned long long m = bmask[j];
      while (m) {
        const int l = __builtin_ctzll(m);
        m &= m - 1;
        const float* wr = wrecT + (size_t)(l * 16 + j) * H_ + h0;
        const float4 w0 = *(const float4*)(wr + 0);
        const float4 w1 = *(const float4*)(wr + 4);
        const float4 w2 = *(const float4*)(wr + 8);
        const float4 w3 = *(const float4*)(wr + 12);
        I[0]  += w0.x; I[1]  += w0.y; I[2]  += w0.z; I[3]  += w0.w;
        I[4]  += w1.x; I[5]  += w1.y; I[6]  += w1.z; I[7]  += w1.w;
        I[8]  += w2.x; I[9]  += w2.y; I[10] += w2.z; I[11] += w2.w;
        I[12] += w3.x; I[13] += w3.y; I[14] += w3.z; I[15] += w3.w;
      }
    }

    // adaptive LIF update + new ballots
#pragma unroll
    for (int j = 0; j < 16; ++j) {
      const float vg = (spk[j] > 0.f) ? 0.f : v[j];
      const float vn = al[j] * vg + al1[j] * (I[j] - av[j]);
      const float sn = (vn > 1.0f) ? 1.0f : 0.0f;
      av[j] = rh[j] * av[j] + rh1[j] * (ba[j] * vn + sn);
      v[j] = vn; spk[j] = sn;
      bmask[j] = __ballot(sn > 0.f);
    }

    // output currents from NEW spikes (lanes 0..19 accumulate their o)
    float io = 0.f;
#pragma unroll
    for (int j = 0; j < 16; ++j) {
      unsigned long long m = bmask[j];
      while (m) {
        const int l = __builtin_ctzll(m);
        m &= m - 1;
        io += woutT[(size_t)(l * 16 + j) * O_ + olane];
      }
    }
    vo = bo * vo + (1.0f - bo) * io;
    osum += vo;
  }

  if (lane < O_) out[(size_t)b * O_ + lane] = osum / (float)T_;
}

// ---------------------------------------------------------------------------
extern "C" void kernel_launch(void* const* d_in, const int* in_sizes, int n_in,
                              void* d_out, int out_size, void* d_ws, size_t ws_size,
                              hipStream_t stream) {
  const float* x        = (const float*)d_in[0];
  const int*   delays   = (const int*)d_in[1];
  const float* w_in     = (const float*)d_in[2];
  const float* w_rec    = (const float*)d_in[3];
  const float* w_out    = (const float*)d_in[4];
  const float* alpha    = (const float*)d_in[5];
  const float* rho      = (const float*)d_in[6];
  const float* beta_a   = (const float*)d_in[7];
  const float* beta_out = (const float*)d_in[8];

  float* ws    = (float*)d_ws;
  float* wrecT = ws;                                 // H*H fp32
  float* woutT = wrecT + (size_t)H_ * H_;            // H*O fp32
  float* Iin   = woutT + (size_t)H_ * O_;            // M*H fp32
  _Float16* A3 = (_Float16*)(Iin + (size_t)M_ * H_); // M*KA fp16
  _Float16* Bt = A3 + (size_t)M_ * KA_;              // H*KB fp16
  float* out   = (float*)d_out;

  transpose_pad<<<(H_ * H_) / 256, 256, 0, stream>>>(w_rec, wrecT, H_, H_, H_);
  transpose_pad<<<(H_ * O_) / 256, 256, 0, stream>>>(w_out, woutT, O_, H_, H_);
  bt_prep<<<(H_ * KB_) / 256, 256, 0, stream>>>(w_in, Bt);
  delay_split<<<M_, 256, 0, stream>>>(x, delays, A3);

  dim3 g(H_ / 128, M_ / 128);   // x = col tile (8), y = row tile (500)
  gemm_split<<<g, 256, 0, stream>>>(A3, Bt, Iin);

  recurrent_w<<<B_, 64, 0, stream>>>(Iin, wrecT, woutT,
                                     alpha, rho, beta_a, beta_out, out);
}

// Round 3
// 1324.631 us; speedup vs baseline: 1.7430x; 1.0337x over previous
//
#include <hip/hip_runtime.h>
#include <stdint.h>

#define B_   128
#define T_   500
#define C_   700
#define CP_  704          // C padded to 16
#define H_   1024
#define O_   20
#define M_   (T_ * B_)    // 64000 rows, row = t*128 + b
#define KA_  (2 * CP_)    // 1408: A' = [hi | lo]
#define KB_  (3 * CP_)    // 2112: Bt = [hi | hi | lo]
#define SCALE_      256.0f
#define INV_SCALE2_ (1.0f / 65536.0f)

typedef _Float16 half8 __attribute__((ext_vector_type(8)));
typedef float    f32x4 __attribute__((ext_vector_type(4)));

// ---------------------------------------------------------------------------
// out[c*R + r] = (c < C) ? in[r*C + c] : 0   (fp32 transpose, zero-pad)
__global__ __launch_bounds__(256) void transpose_pad(
    const float* __restrict__ in, float* __restrict__ out,
    int R, int C, int Cpad) {
  int idx = blockIdx.x * 256 + threadIdx.x;
  if (idx >= Cpad * R) return;
  int c = idx / R;
  int r = idx - c * R;
  out[idx] = (c < C) ? in[(size_t)r * C + c] : 0.0f;
}

// ---------------------------------------------------------------------------
// Bt[n][k]: k in [0,704) -> hi(w*256); [704,1408) -> hi; [1408,2112) -> lo
__global__ __launch_bounds__(256) void bt_prep(
    const float* __restrict__ w_in, _Float16* __restrict__ Bt) {
  int idx = blockIdx.x * 256 + threadIdx.x;   // over H_*KB_
  if (idx >= H_ * KB_) return;
  int n = idx / KB_;
  int k = idx - n * KB_;
  int blk = k / CP_;
  int c = k - blk * CP_;
  float v = (c < C_) ? w_in[(size_t)n * C_ + c] * SCALE_ : 0.0f;
  _Float16 hi = (_Float16)v;
  Bt[idx] = (blk == 2) ? (_Float16)(v - (float)hi) : hi;
}

// ---------------------------------------------------------------------------
// A3[m][k]: k in [0,704) -> hi(xd*256); [704,1408) -> lo.  m = t*128+b.
__global__ __launch_bounds__(256) void delay_split(
    const float* __restrict__ x, const int* __restrict__ delays,
    _Float16* __restrict__ A3) {
  int row = blockIdx.x;
  int t = row >> 7;
  int b = row & 127;
  const float* xb = x + (size_t)b * (T_ * C_);
  _Float16* dst = A3 + (size_t)row * KA_;
  for (int c = threadIdx.x; c < CP_; c += 256) {
    float v = 0.0f;
    if (c < C_) {
      int ts = t - delays[c];
      if (ts >= 0) v = xb[(size_t)ts * C_ + c];
    }
    v *= SCALE_;
    _Float16 hi = (_Float16)v;
    dst[c] = hi;
    dst[CP_ + c] = (_Float16)(v - (float)hi);
  }
}

// ---------------------------------------------------------------------------
__device__ __forceinline__ void gload16(const void* g, const void* l) {
  __builtin_amdgcn_global_load_lds(
      (const __attribute__((address_space(1))) void*)(uintptr_t)g,
      (__attribute__((address_space(3))) void*)(uint32_t)(uintptr_t)l,
      16, 0, 0);
}

// fp16 MFMA GEMM: Cm[M_,H_] = A3[M_,KA_ (hi reused)] x Bt[H_,KB_]^T, *2^-16.
__global__ __launch_bounds__(256) void gemm_split(
    const _Float16* __restrict__ A3, const _Float16* __restrict__ Bt,
    float* __restrict__ Cm) {
  __shared__ __align__(16) _Float16 As[128 * 32];
  __shared__ __align__(16) _Float16 Bs[128 * 32];

  const int tid  = threadIdx.x;
  const int wave = tid >> 6, lane = tid & 63;
  const int col0 = blockIdx.x * 128;
  const int row0 = blockIdx.y * 128;
  const int q = lane >> 4, r = lane & 15;
  const int wm0 = (wave >> 1) * 64, wn0 = (wave & 1) * 64;

  f32x4 acc[4][4] = {};

  const int pi0 = wave * 2;
  const int srow = lane >> 2;
  const int gch8 = (((lane & 3) ^ ((lane >> 3) & 3))) * 8;

  const int ch8 = (q ^ ((r >> 1) & 3)) * 8;
  int aoff[4], boff[4];
#pragma unroll
  for (int i = 0; i < 4; ++i) {
    aoff[i] = (wm0 + i * 16 + r) * 32 + ch8;
    boff[i] = (wn0 + i * 16 + r) * 32 + ch8;
  }

  const size_t arow0 = (size_t)(row0 + pi0 * 16 + srow);
  const size_t arow1 = arow0 + 16;
  const size_t brow0 = (size_t)(col0 + pi0 * 16 + srow);
  const size_t brow1 = brow0 + 16;

  for (int kb = 0; kb < KB_ / 32; ++kb) {
    const int k0 = kb * 32;
    const int kA = (k0 < KA_) ? k0 : (k0 - KA_);
    __syncthreads();
    gload16(A3 + arow0 * KA_ + kA + gch8, &As[(pi0 + 0) * 512]);
    gload16(A3 + arow1 * KA_ + kA + gch8, &As[(pi0 + 1) * 512]);
    gload16(Bt + brow0 * KB_ + k0 + gch8, &Bs[(pi0 + 0) * 512]);
    gload16(Bt + brow1 * KB_ + k0 + gch8, &Bs[(pi0 + 1) * 512]);
    __syncthreads();

    half8 af[4], bf[4];
#pragma unroll
    for (int i = 0; i < 4; ++i) af[i] = *(const half8*)&As[aoff[i]];
#pragma unroll
    for (int j = 0; j < 4; ++j) bf[j] = *(const half8*)&Bs[boff[j]];
#pragma unroll
    for (int i = 0; i < 4; ++i)
#pragma unroll
      for (int j = 0; j < 4; ++j)
        acc[i][j] = __builtin_amdgcn_mfma_f32_16x16x32_f16(af[i], bf[j],
                                                           acc[i][j], 0, 0, 0);
  }

#pragma unroll
  for (int i = 0; i < 4; ++i) {
    const int mrow = row0 + wm0 + i * 16 + q * 4;
#pragma unroll
    for (int j = 0; j < 4; ++j) {
      const int ncol = col0 + wn0 + j * 16 + r;
      float* cp = Cm + (size_t)mrow * H_ + ncol;
#pragma unroll
      for (int rg = 0; rg < 4; ++rg)
        cp[(size_t)rg * H_] = acc[i][j][rg] * INV_SCALE2_;
    }
  }
}

// ---------------------------------------------------------------------------
// One wave per batch sample; 16 neurons per lane (h = lane*16 + j).
// Spike list built scalar-side from ballots; gathers batched 4 rows at a time
// (latency = max, not sum). w_out gather merged into the same batch by
// deferring the readout filter one step.
__global__ __launch_bounds__(64, 1) void recurrent_w(
    const float* __restrict__ Iin,   // [M_][H_], row = t*128 + b
    const float* __restrict__ wrecT, // [H_][H_]  wrecT[h'][h] = w_rec[h][h']
    const float* __restrict__ woutT, // [H_][O_]  woutT[h][o]  = w_out[o][h]
    const float* __restrict__ alpha, const float* __restrict__ rho,
    const float* __restrict__ beta_a, const float* __restrict__ beta_out,
    float* __restrict__ out) {
  const int b = blockIdx.x;
  const int lane = threadIdx.x;
  const int h0 = lane * 16;

  float v[16], av[16], spk[16];
  float al[16], al1[16], rh[16], rh1[16], ba[16];
#pragma unroll
  for (int j = 0; j < 16; ++j) {
    v[j] = 0.f; av[j] = 0.f; spk[j] = 0.f;
    al[j] = alpha[h0 + j]; al1[j] = 1.0f - al[j];
    rh[j] = rho[h0 + j];   rh1[j] = 1.0f - rh[j];
    ba[j] = beta_a[h0 + j];
  }
  unsigned long long bmask[16];
#pragma unroll
  for (int j = 0; j < 16; ++j) bmask[j] = 0ull;

  const int olane = (lane < O_) ? lane : 0;
  float bo = 0.f, vo = 0.f, osum = 0.f;
  if (lane < O_) bo = beta_out[lane];

  const float* base = Iin + (size_t)b * H_ + h0;
  float4 nx0 = *(const float4*)(base + 0);
  float4 nx1 = *(const float4*)(base + 4);
  float4 nx2 = *(const float4*)(base + 8);
  float4 nx3 = *(const float4*)(base + 12);

  for (int t = 0; t < T_; ++t) {
    float I[16];
    I[0]  = nx0.x; I[1]  = nx0.y; I[2]  = nx0.z; I[3]  = nx0.w;
    I[4]  = nx1.x; I[5]  = nx1.y; I[6]  = nx1.z; I[7]  = nx1.w;
    I[8]  = nx2.x; I[9]  = nx2.y; I[10] = nx2.z; I[11] = nx2.w;
    I[12] = nx3.x; I[13] = nx3.y; I[14] = nx3.z; I[15] = nx3.w;

    // ---- batched gather over previous-step spikes (wave-uniform masks) ----
    float io = 0.f;   // deferred: output current of spike set S(t-1)
    unsigned long long mm0 = bmask[0],  mm1 = bmask[1],  mm2 = bmask[2],
                       mm3 = bmask[3],  mm4 = bmask[4],  mm5 = bmask[5],
                       mm6 = bmask[6],  mm7 = bmask[7],  mm8 = bmask[8],
                       mm9 = bmask[9],  mm10 = bmask[10], mm11 = bmask[11],
                       mm12 = bmask[12], mm13 = bmask[13], mm14 = bmask[14],
                       mm15 = bmask[15];
    unsigned long long any = (mm0 | mm1) | (mm2 | mm3) | (mm4 | mm5) |
                             (mm6 | mm7) | (mm8 | mm9) | (mm10 | mm11) |
                             (mm12 | mm13) | (mm14 | mm15);
    while (any) {
      // scalar-build up to 4 spike indices into a packed 64-bit word
      unsigned long long packed = 0ull;
      int cnt = 0;
      unsigned long long* mp[16] = {&mm0,&mm1,&mm2,&mm3,&mm4,&mm5,&mm6,&mm7,
                                    &mm8,&mm9,&mm10,&mm11,&mm12,&mm13,&mm14,&mm15};
#pragma unroll
      for (int j = 0; j < 16; ++j) {
        while (*mp[j] && cnt < 4) {
          const int l = __builtin_ctzll(*mp[j]);
          *mp[j] &= *mp[j] - 1;
          packed |= (unsigned long long)(unsigned)(l * 16 + j) << (10 * cnt);
          ++cnt;
        }
      }
      const int hA = (int)(packed & 1023u);
      const int hB = (int)((packed >> 10) & 1023u);
      const int hC = (int)((packed >> 20) & 1023u);
      const int hD = (int)((packed >> 30) & 1023u);
      const float sB = (cnt > 1) ? 1.f : 0.f;
      const float sC = (cnt > 2) ? 1.f : 0.f;
      const float sD = (cnt > 3) ? 1.f : 0.f;

      // issue ALL loads before any accumulation (single vmcnt drain)
      const float* rA = wrecT + (size_t)hA * H_ + h0;
      const float* rB = wrecT + (size_t)hB * H_ + h0;
      const float* rC = wrecT + (size_t)hC * H_ + h0;
      const float* rD = wrecT + (size_t)hD * H_ + h0;
      float4 wA0 = *(const float4*)(rA + 0),  wA1 = *(const float4*)(rA + 4);
      float4 wA2 = *(const float4*)(rA + 8),  wA3 = *(const float4*)(rA + 12);
      float4 wB0 = *(const float4*)(rB + 0),  wB1 = *(const float4*)(rB + 4);
      float4 wB2 = *(const float4*)(rB + 8),  wB3 = *(const float4*)(rB + 12);
      float4 wC0 = *(const float4*)(rC + 0),  wC1 = *(const float4*)(rC + 4);
      float4 wC2 = *(const float4*)(rC + 8),  wC3 = *(const float4*)(rC + 12);
      float4 wD0 = *(const float4*)(rD + 0),  wD1 = *(const float4*)(rD + 4);
      float4 wD2 = *(const float4*)(rD + 8),  wD3 = *(const float4*)(rD + 12);
      float oA = woutT[(size_t)hA * O_ + olane];
      float oB = woutT[(size_t)hB * O_ + olane];
      float oC = woutT[(size_t)hC * O_ + olane];
      float oD = woutT[(size_t)hD * O_ + olane];

      I[0] += wA0.x; I[1] += wA0.y; I[2]  += wA0.z; I[3]  += wA0.w;
      I[4] += wA1.x; I[5] += wA1.y; I[6]  += wA1.z; I[7]  += wA1.w;
      I[8] += wA2.x; I[9] += wA2.y; I[10] += wA2.z; I[11] += wA2.w;
      I[12]+= wA3.x; I[13]+= wA3.y; I[14] += wA3.z; I[15] += wA3.w;
      io += oA;
      I[0] += sB*wB0.x; I[1] += sB*wB0.y; I[2]  += sB*wB0.z; I[3]  += sB*wB0.w;
      I[4] += sB*wB1.x; I[5] += sB*wB1.y; I[6]  += sB*wB1.z; I[7]  += sB*wB1.w;
      I[8] += sB*wB2.x; I[9] += sB*wB2.y; I[10] += sB*wB2.z; I[11] += sB*wB2.w;
      I[12]+= sB*wB3.x; I[13]+= sB*wB3.y; I[14] += sB*wB3.z; I[15] += sB*wB3.w;
      io += sB * oB;
      I[0] += sC*wC0.x; I[1] += sC*wC0.y; I[2]  += sC*wC0.z; I[3]  += sC*wC0.w;
      I[4] += sC*wC1.x; I[5] += sC*wC1.y; I[6]  += sC*wC1.z; I[7]  += sC*wC1.w;
      I[8] += sC*wC2.x; I[9] += sC*wC2.y; I[10] += sC*wC2.z; I[11] += sC*wC2.w;
      I[12]+= sC*wC3.x; I[13]+= sC*wC3.y; I[14] += sC*wC3.z; I[15] += sC*wC3.w;
      io += sC * oC;
      I[0] += sD*wD0.x; I[1] += sD*wD0.y; I[2]  += sD*wD0.z; I[3]  += sD*wD0.w;
      I[4] += sD*wD1.x; I[5] += sD*wD1.y; I[6]  += sD*wD1.z; I[7]  += sD*wD1.w;
      I[8] += sD*wD2.x; I[9] += sD*wD2.y; I[10] += sD*wD2.z; I[11] += sD*wD2.w;
      I[12]+= sD*wD3.x; I[13]+= sD*wD3.y; I[14] += sD*wD3.z; I[15] += sD*wD3.w;
      io += sD * oD;

      any = (mm0 | mm1) | (mm2 | mm3) | (mm4 | mm5) | (mm6 | mm7) |
            (mm8 | mm9) | (mm10 | mm11) | (mm12 | mm13) | (mm14 | mm15);
    }

    // prefetch next timestep (issued AFTER gathers -> gathers can retire at
    // vmcnt(4) while these stay in flight)
    if (t + 1 < T_) {
      const float* nb = base + (size_t)(t + 1) * (B_ * H_);
      nx0 = *(const float4*)(nb + 0);
      nx1 = *(const float4*)(nb + 4);
      nx2 = *(const float4*)(nb + 8);
      nx3 = *(const float4*)(nb + 12);
    }

    // deferred readout filter: applies io(S(t-1)); t=0 contributes exact 0
    vo = bo * vo + (1.0f - bo) * io;
    osum += vo;

    // adaptive LIF update + new ballots
#pragma unroll
    for (int j = 0; j < 16; ++j) {
      const float vg = (spk[j] > 0.f) ? 0.f : v[j];
      const float vn = al[j] * vg + al1[j] * (I[j] - av[j]);
      const float sn = (vn > 1.0f) ? 1.0f : 0.0f;
      av[j] = rh[j] * av[j] + rh1[j] * (ba[j] * vn + sn);
      v[j] = vn; spk[j] = sn;
      bmask[j] = __ballot(sn > 0.f);
    }
  }

  // epilogue: readout contribution of the final spike set S(T-1)
  {
    float io = 0.f;
#pragma unroll
    for (int j = 0; j < 16; ++j) {
      unsigned long long m = bmask[j];
      while (m) {
        const int l = __builtin_ctzll(m);
        m &= m - 1;
        io += woutT[(size_t)(l * 16 + j) * O_ + olane];
      }
    }
    vo = bo * vo + (1.0f - bo) * io;
    osum += vo;
  }

  if (lane < O_) out[(size_t)b * O_ + lane] = osum / (float)T_;
}

// ---------------------------------------------------------------------------
extern "C" void kernel_launch(void* const* d_in, const int* in_sizes, int n_in,
                              void* d_out, int out_size, void* d_ws, size_t ws_size,
                              hipStream_t stream) {
  const float* x        = (const float*)d_in[0];
  const int*   delays   = (const int*)d_in[1];
  const float* w_in     = (const float*)d_in[2];
  const float* w_rec    = (const float*)d_in[3];
  const float* w_out    = (const float*)d_in[4];
  const float* alpha    = (const float*)d_in[5];
  const float* rho      = (const float*)d_in[6];
  const float* beta_a   = (const float*)d_in[7];
  const float* beta_out = (const float*)d_in[8];

  float* ws    = (float*)d_ws;
  float* wrecT = ws;                                 // H*H fp32
  float* woutT = wrecT + (size_t)H_ * H_;            // H*O fp32
  float* Iin   = woutT + (size_t)H_ * O_;            // M*H fp32
  _Float16* A3 = (_Float16*)(Iin + (size_t)M_ * H_); // M*KA fp16
  _Float16* Bt = A3 + (size_t)M_ * KA_;              // H*KB fp16
  float* out   = (float*)d_out;

  transpose_pad<<<(H_ * H_) / 256, 256, 0, stream>>>(w_rec, wrecT, H_, H_, H_);
  transpose_pad<<<(H_ * O_) / 256, 256, 0, stream>>>(w_out, woutT, O_, H_, H_);
  bt_prep<<<(H_ * KB_) / 256, 256, 0, stream>>>(w_in, Bt);
  delay_split<<<M_, 256, 0, stream>>>(x, delays, A3);

  dim3 g(H_ / 128, M_ / 128);
  gemm_split<<<g, 256, 0, stream>>>(A3, Bt, Iin);

  recurrent_w<<<B_, 64, 0, stream>>>(Iin, wrecT, woutT,
                                     alpha, rho, beta_a, beta_out, out);
}